// Round 8
// baseline (217.648 us; speedup 1.0000x reference)
//
#include <hip/hip_runtime.h>
#include <hip/hip_fp16.h>

#define HC 16
#define CIN 16
#define BD 31
#define HH 128
#define WW 128
#define PLANE (HH*WW)           // 16384
#define CH_STRIDE (BD*PLANE)    // 507904

typedef __attribute__((ext_vector_type(8))) short bf16x8;   // 8 bf16 = 4 VGPR
typedef __attribute__((ext_vector_type(16))) float f32x16;  // MFMA 32x32 acc

__device__ __forceinline__ float sigmoidf_fast(float x) {
    return 1.0f / (1.0f + __expf(-x));
}
__device__ __forceinline__ float tanhf_fast(float x) {
    return 2.0f / (1.0f + __expf(-2.0f * x)) - 1.0f;
}
__device__ __forceinline__ ushort f2bf(float f) {   // RNE float->bf16
    unsigned u = __float_as_uint(f);
    u = (u + 0x7fffu + ((u >> 16) & 1u)) >> 16;
    return (ushort)u;
}
// exact-gelu via Abramowitz-Stegun 7.1.26 erf (|eps|<=1.5e-7)
__device__ __forceinline__ float gelu_as(float s) {
    float z  = 0.70710678118f * s;
    float az = fabsf(z);
    float t  = __builtin_amdgcn_rcpf(fmaf(0.3275911f, az, 1.0f));
    float p  = t * (0.254829592f + t * (-0.284496736f + t * (1.421413741f
             + t * (-1.453152027f + t * 1.061405429f))));
    float e  = __expf(-z * z);
    float er = copysignf(1.0f - p * e, z);
    return 0.5f * s * (1.0f + er);
}

// ---------------------------------------------------------------------------
// Merged weight prep (one launch).
// idx < 13824: conv wtab[kd][tap][lane][j], co=lane&31, ci=8*(lane>>5)+j.
// next 2048:  MLP wtab2: tbl0 w1^T, tbl1/2 w2 (permuted k, rows>=16 zero),
//             tbl3 w3^T ([a|wg] rows). Shared-k-permutation with B side.
// ---------------------------------------------------------------------------
__global__ void wprep_all(const float* __restrict__ cw,
                          const float* __restrict__ w1,
                          const float* __restrict__ w2,
                          const float* __restrict__ w3,
                          ushort* __restrict__ wtab,
                          ushort* __restrict__ wtab2)
{
    int idx = blockIdx.x * 256 + threadIdx.x;
    if (idx < 13824) {
        int j    = idx & 7;
        int lane = (idx >> 3) & 63;
        int t    = (idx >> 9) % 9;
        int kd   = (idx >> 9) / 9;
        int co = lane & 31;
        int ci = 8 * (lane >> 5) + j;
        int kh = t / 3, kw = t % 3;
        wtab[idx] = f2bf(cw[(co * CIN + ci) * 27 + kd * 9 + kh * 3 + kw]);
        return;
    }
    idx -= 13824;
    if (idx >= 2048) return;
    int e    = idx & 7;
    int lane = (idx >> 3) & 63;
    int tbl  = idx >> 9;
    int m  = lane & 31;
    int hi = lane >> 5;
    float v = 0.f;
    if (tbl == 0)      v = w1[(8 * hi + e) * 32 + m];
    else if (tbl == 3) v = w3[(8 * hi + e) * 32 + m];
    else {
        int mf = tbl - 1;
        if (m < 16) v = w2[((e & 3) + 8 * (e >> 2) + 4 * hi + 16 * mf) * 16 + m];
    }
    wtab2[idx] = f2bf(v);
}

// ---------------------------------------------------------------------------
// Slab swizzle: byte = (row*4224 + wcol*32 + cio) ^ ((wcol&0xE)<<3). Injective,
// bank-conflict-free (measured 0). row*4224(+buf)/half*2048/nn*1024 offsets
// don't touch the XOR bits.
// ---------------------------------------------------------------------------
#define SLAB_HALF (4 * 4224)    // 16896 B per buffer

// ---------------------------------------------------------------------------
// xprep: fp32 [b][ci][d][h][w] -> bf16 rows xT[b][d][h][4096B], ci innermost,
// slab swizzle pre-baked (swizzle-source + linear gload_lds dest, rule #21).
// ---------------------------------------------------------------------------
__global__ __launch_bounds__(256)
void xprep_kernel(const float* __restrict__ inp, char* __restrict__ xT)
{
    __shared__ float tile[16][256];
    int t  = threadIdx.x;
    int hp = blockIdx.x & 63;
    int g  = blockIdx.x >> 6;
    int d  = g % BD;
    int b  = g / BD;

    size_t src = (size_t)b * CIN * CH_STRIDE + (size_t)d * PLANE + hp * 256;
    #pragma unroll
    for (int c = 0; c < 16; ++c)
        tile[c][t] = inp[src + (size_t)c * CH_STRIDE + t];
    __syncthreads();

    int w  = t & 127;
    int rr = t >> 7;
    char* rowp = xT + (((size_t)(b * BD + d) * 128) + hp * 2 + rr) * 4096;
    #pragma unroll
    for (int q = 0; q < 2; ++q) {
        uint4 pk;
        pk.x = (unsigned)f2bf(tile[q*8+0][t]) | ((unsigned)f2bf(tile[q*8+1][t]) << 16);
        pk.y = (unsigned)f2bf(tile[q*8+2][t]) | ((unsigned)f2bf(tile[q*8+3][t]) << 16);
        pk.z = (unsigned)f2bf(tile[q*8+4][t]) | ((unsigned)f2bf(tile[q*8+5][t]) << 16);
        pk.w = (unsigned)f2bf(tile[q*8+6][t]) | ((unsigned)f2bf(tile[q*8+7][t]) << 16);
        unsigned off = ((unsigned)((w + 1) * 32 + q * 16) ^ (((unsigned)(w + 1) & 0xE) << 3)) - 32;
        *(uint4*)(rowp + off) = pk;
    }
}

// ---------------------------------------------------------------------------
// Conv via MFMA, double-buffered slab + counted vmcnt (T3/T4-style).
// Per kd: issue next-plane stage into buf^1, wait vmcnt(13) (drains only the
// 4 OLDEST ops = current slab; A-frag + next-stage loads stay in flight),
// raw s_barrier, 18 MFMA, s_barrier. Boundary rows gload into a dump region
// to keep per-wave vmcnt counts uniform (always 4 per stage).
// ---------------------------------------------------------------------------
__device__ __forceinline__ void gload_lds16(const void* g, void* l) {
    __builtin_amdgcn_global_load_lds(
        (const __attribute__((address_space(1))) unsigned int*)g,
        (__attribute__((address_space(3))) unsigned int*)l, 16, 0, 0);
}

__global__ __launch_bounds__(256, 4)
void conv_gates_mfma_fast(const char* __restrict__ xT,
                          const ushort* __restrict__ wtab,
                          __half2* __restrict__ zf)
{
    __shared__ __align__(16) char slab[2][SLAB_HALF];
    __shared__ __align__(16) char dump[1024];

    // grid 7936 = 8 XCD * 992: consecutive logical ids share an XCD's L2
    int p = blockIdx.x;
    int logical = (p & 7) * 992 + (p >> 3);
    int ht = logical & 63;          // 64 h-tiles of 2 rows
    int g  = logical >> 6;
    int d  = g % BD;
    int b  = g / BD;
    int h0 = ht * 2;

    int lane = threadIdx.x & 63;
    int wid  = threadIdx.x >> 6;
    int row  = wid >> 1;            // output row within tile
    int half = wid & 1;             // w-half
    int wl   = lane & 31;
    int cio  = (lane >> 5) * 16;

    // per-lane LDS read byte-offsets (within one buffer) for dw=0,1,2
    unsigned bpo[3];
    #pragma unroll
    for (int dw = 0; dw < 3; ++dw) {
        unsigned wc = (unsigned)(wl + dw);
        bpo[dw] = (unsigned)(row * 4224 + half * 2048)
                + ((wc * 32 + cio) ^ ((wc & 0xE) << 3));
    }

    // zero edge regions of BOTH buffers: per row, [0,32) and [4128,4224).
    {
        int t = threadIdx.x;          // 256 = 2 buf x 4 rows x 32 words
        int bf = t >> 7;
        int r  = (t >> 5) & 3;
        int k  = t & 31;
        int off = (k < 8) ? (k * 4) : (4128 + (k - 8) * 4);
        *(int*)(slab[bf] + r * 4224 + off) = 0;
        asm volatile("s_waitcnt lgkmcnt(0)" ::: "memory");
    }

    // plane list (2 at d-edges, else 3)
    int dds[3]; int nkd = 0;
    #pragma unroll
    for (int kd = 0; kd < 3; ++kd) {
        int dd = d + kd - 1;
        if (dd >= 0 && dd < BD) dds[nkd++] = dd;
    }

    auto STAGE = [&](char* buf, int dd) {
        const char* plane = xT + ((size_t)(b * BD + dd) * 128) * 4096;
        #pragma unroll
        for (int i = 0; i < 4; ++i) {       // 4 chunks per wave: ch=wid, rows 0..3
            int r  = i;
            int h  = h0 - 1 + r;
            char* dst = buf + r * 4224 + 32 + wid * 1024;
            if ((unsigned)h < HH) {
                gload_lds16(plane + (size_t)h * 4096 + wid * 1024 + lane * 16, dst);
            } else {
                // dummy load keeps vmcnt uniform; real row zero-filled
                gload_lds16(xT + wid * 1024 + lane * 16, dump);
                *(uint4*)(dst + lane * 16) = uint4{0, 0, 0, 0};
            }
        }
        asm volatile("s_waitcnt lgkmcnt(0)" ::: "memory");  // drain zero ds_writes
    };

    f32x16 acc[2];
    #pragma unroll
    for (int n = 0; n < 2; ++n)
        #pragma unroll
        for (int r = 0; r < 16; ++r) acc[n][r] = 0.f;

    const bf16x8* wt = (const bf16x8*)wtab;

    STAGE(slab[0], dds[0]);   // prologue: first plane in flight

    #pragma unroll 1
    for (int ik = 0; ik < nkd; ++ik) {
        const char* cbuf = slab[ik & 1];
        int kd = dds[ik] - d + 1;       // tap-plane index 0..2

        bf16x8 af[9];
        #pragma unroll
        for (int t = 0; t < 9; ++t)
            af[t] = wt[(kd * 9 + t) * 64 + lane];

        if (ik + 1 < nkd) {
            STAGE(slab[(ik + 1) & 1], dds[ik + 1]);
            // FIFO: [cur stage:4][af:9][next stage:4] -> vmcnt(13) drains
            // exactly the 4 oldest (current slab). af/next stay in flight.
            asm volatile("s_waitcnt vmcnt(13)" ::: "memory");
        } else {
            // FIFO: [cur stage:4][af:9] -> vmcnt(9) drains current slab.
            asm volatile("s_waitcnt vmcnt(9)" ::: "memory");
        }
        __builtin_amdgcn_s_barrier();        // all waves' current slab landed
        __builtin_amdgcn_sched_barrier(0);

        __builtin_amdgcn_s_setprio(1);
        #pragma unroll
        for (int t = 0; t < 9; ++t) {
            const unsigned bo = bpo[t % 3] + (t / 3) * 4224;
            #pragma unroll
            for (int nn = 0; nn < 2; ++nn) {
                bf16x8 bfr = *(const bf16x8*)(cbuf + bo + nn * 1024);
                acc[nn] = __builtin_amdgcn_mfma_f32_32x32x16_bf16(af[t], bfr, acc[nn], 0, 0, 0);
            }
        }
        __builtin_amdgcn_s_setprio(0);
        __builtin_amdgcn_sched_barrier(0);
        __builtin_amdgcn_s_barrier();        // safe to overwrite cbuf next iter
    }

    // epilogue: point-major zf[bd][pt][c] half2. C/D map: col=lane&31,
    // row=(r&3)+8*(r>>2)+4*hi => contiguous c-quads -> 2x16B stores per tile.
    int h = h0 + row;
    int co_hi = 4 * (lane >> 5);
    size_t tbase = ((size_t)(b * BD + d) * PLANE + (size_t)h * WW);
    #pragma unroll
    for (int nn = 0; nn < 2; ++nn) {
        int w = (2 * half + nn) * 32 + wl;
        __half2* pbase = zf + (tbase + w) * 16 + co_hi;
        union { uint4 u; __half2 h2[4]; } s0, s1;
        #pragma unroll
        for (int r = 0; r < 4; ++r) {
            s0.h2[r] = __floats2half2_rn(tanhf_fast(acc[nn][r]),
                                         sigmoidf_fast(acc[nn][r + 8]));
            s1.h2[r] = __floats2half2_rn(tanhf_fast(acc[nn][r + 4]),
                                         sigmoidf_fast(acc[nn][r + 12]));
        }
        *(uint4*)pbase       = s0.u;
        *(uint4*)(pbase + 8) = s1.u;
    }
}

// ---------------------------------------------------------------------------
// FUSED scan+MLP. Wave = 32 points; lane (p,hi) owns channels 8hi..8hi+7 of
// point p — exactly the MLP B-frag layout, so h never leaves registers.
// ---------------------------------------------------------------------------
__global__ __launch_bounds__(256)
void scanmlp_kernel(const __half2* __restrict__ zf,
                    const ushort* __restrict__ wtab2,
                    float* __restrict__ out,
                    const int* __restrict__ rev_p)
{
    int lane = threadIdx.x & 63;
    int wid  = threadIdx.x >> 6;
    int p    = lane & 31;
    int hi   = lane >> 5;
    int rev  = rev_p[0];

    size_t gw  = (size_t)blockIdx.x * 4 + wid;   // 2048 waves
    size_t ptg = gw * 32 + p;                    // global point 0..65535
    int b   = (int)(ptg >> 14);
    int pix = (int)(ptg & 16383);

    const bf16x8* W = (const bf16x8*)wtab2;
    bf16x8 af1  = W[lane];
    bf16x8 af2a = W[64 + lane];
    bf16x8 af2b = W[128 + lane];
    bf16x8 af3  = W[192 + lane];

    const char* zbase = (const char*)zf
        + ((size_t)(b * BD) * PLANE + pix) * 64 + hi * 32;
    long long dstep = (long long)PLANE * 64;
    long long cur   = rev ? (long long)(BD - 1) * dstep : 0;
    long long sgn   = rev ? -dstep : dstep;

    float* obase0 = out + (size_t)b * HC * CH_STRIDE + pix;

    float h[8];
    #pragma unroll
    for (int j = 0; j < 8; ++j) h[j] = 0.f;

    f32x16 zacc;
    #pragma unroll
    for (int r = 0; r < 16; ++r) zacc[r] = 0.f;

    uint4 nz0 = *(const uint4*)(zbase + cur);
    uint4 nz1 = *(const uint4*)(zbase + cur + 16);

    #pragma unroll 1
    for (int dd = 0; dd < BD; ++dd) {
        unsigned zw[8] = {nz0.x, nz0.y, nz0.z, nz0.w,
                          nz1.x, nz1.y, nz1.z, nz1.w};
        int d = rev ? (BD - 1 - dd) : dd;
        cur += sgn;
        if (dd + 1 < BD) {
            nz0 = *(const uint4*)(zbase + cur);
            nz1 = *(const uint4*)(zbase + cur + 16);
        }

        union { bf16x8 v; unsigned u[4]; } bx;
        #pragma unroll
        for (int j = 0; j < 8; ++j) {
            __half2 v = *(__half2*)&zw[j];
            float z = __low2float(v);
            float f = __high2float(v);
            h[j] = f * h[j] + (1.f - f) * z;
        }
        #pragma unroll
        for (int q = 0; q < 4; ++q)
            bx.u[q] = (unsigned)f2bf(h[2 * q]) | ((unsigned)f2bf(h[2 * q + 1]) << 16);

        f32x16 acc1 = __builtin_amdgcn_mfma_f32_32x32x16_bf16(af1, bx.v, zacc, 0, 0, 0);
        f32x16 acc3 = __builtin_amdgcn_mfma_f32_32x32x16_bf16(af3, bx.v, zacc, 0, 0, 0);

        union { bf16x8 v; unsigned u[4]; } b2a, b2b;
        #pragma unroll
        for (int q = 0; q < 4; ++q) {
            float g0 = gelu_as(acc1[2 * q]);
            float g1 = gelu_as(acc1[2 * q + 1]);
            float g8 = gelu_as(acc1[8 + 2 * q]);
            float g9 = gelu_as(acc1[8 + 2 * q + 1]);
            b2a.u[q] = (unsigned)f2bf(g0) | ((unsigned)f2bf(g1) << 16);
            b2b.u[q] = (unsigned)f2bf(g8) | ((unsigned)f2bf(g9) << 16);
        }

        f32x16 acc2 = __builtin_amdgcn_mfma_f32_32x32x16_bf16(af2a, b2a.v, zacc, 0, 0, 0);
        acc2 = __builtin_amdgcn_mfma_f32_32x32x16_bf16(af2b, b2b.v, acc2, 0, 0, 0);

        float* ob = obase0 + (size_t)d * PLANE;
        #pragma unroll
        for (int r = 0; r < 8; ++r) {
            int c = (r & 3) + 8 * (r >> 2) + 4 * hi;
            ob[(size_t)c * CH_STRIDE] = acc2[r] + acc3[r] * sigmoidf_fast(acc3[r + 8]);
        }
    }
}

// ---------------------------------------------------------------------------
// Fallback pair (ws too small for the zf buffer): scan d_out(zf)->hbuf(bf16),
// then MLP hbuf->d_out. Identical numerics to fused path.
// ---------------------------------------------------------------------------
__global__ __launch_bounds__(256)
void scan_kernel(const __half2* __restrict__ zf, ushort* __restrict__ hbuf,
                 const int* __restrict__ rev_p)
{
    int tid = blockIdx.x * 256 + threadIdx.x;
    int c   = tid & 15;
    int pt  = (tid >> 4) & 16383;
    int b   = tid >> 18;
    int rev = rev_p[0];

    const unsigned* zfw = (const unsigned*)zf;
    size_t col = ((size_t)b * BD) * PLANE * 16 + (size_t)pt * 16 + c;
    long long cur = (long long)col + (rev ? (long long)(BD - 1) * PLANE * 16 : 0);
    long long dstep = rev ? -(long long)PLANE * 16 : (long long)PLANE * 16;

    float h = 0.f;
    unsigned nz = zfw[cur];
    #pragma unroll 1
    for (int dd = 0; dd < BD; ++dd) {
        unsigned cz = nz;
        long long at = cur;
        cur += dstep;
        if (dd + 1 < BD) nz = zfw[cur];

        __half2 v = *(__half2*)&cz;
        float z = __low2float(v);
        float f = __high2float(v);
        h = f * h + (1.f - f) * z;
        hbuf[at] = f2bf(h);
    }
}

__global__ __launch_bounds__(256)
void mlp_mfma_kernel(const char* __restrict__ hbuf,
                     const ushort* __restrict__ wtab2,
                     float* __restrict__ out)
{
    int lane = threadIdx.x & 63;
    int wid  = threadIdx.x >> 6;
    int p    = lane & 31;
    int hi   = lane >> 5;

    size_t tile = (size_t)blockIdx.x * 4 + wid;
    size_t ptg  = tile * 32 + p;

    const bf16x8* W = (const bf16x8*)wtab2;
    bf16x8 af1  = W[lane];
    bf16x8 af2a = W[64 + lane];
    bf16x8 af2b = W[128 + lane];
    bf16x8 af3  = W[192 + lane];
    bf16x8 bx   = *(const bf16x8*)(hbuf + ptg * 32 + hi * 16);

    f32x16 zacc;
    #pragma unroll
    for (int r = 0; r < 16; ++r) zacc[r] = 0.f;

    f32x16 acc1 = __builtin_amdgcn_mfma_f32_32x32x16_bf16(af1, bx, zacc, 0, 0, 0);
    f32x16 acc3 = __builtin_amdgcn_mfma_f32_32x32x16_bf16(af3, bx, zacc, 0, 0, 0);

    union { bf16x8 v; unsigned u[4]; } b2a, b2b;
    #pragma unroll
    for (int q = 0; q < 4; ++q) {
        float g0 = gelu_as(acc1[2 * q]);
        float g1 = gelu_as(acc1[2 * q + 1]);
        float g8 = gelu_as(acc1[8 + 2 * q]);
        float g9 = gelu_as(acc1[8 + 2 * q + 1]);
        b2a.u[q] = (unsigned)f2bf(g0) | ((unsigned)f2bf(g1) << 16);
        b2b.u[q] = (unsigned)f2bf(g8) | ((unsigned)f2bf(g9) << 16);
    }

    f32x16 acc2 = __builtin_amdgcn_mfma_f32_32x32x16_bf16(af2a, b2a.v, zacc, 0, 0, 0);
    acc2 = __builtin_amdgcn_mfma_f32_32x32x16_bf16(af2b, b2b.v, acc2, 0, 0, 0);

    int bd  = (int)(ptg >> 14);
    int pix = (int)(ptg & 16383);
    int b   = bd / BD;
    int d   = bd % BD;
    float* obase = out + (size_t)b * HC * CH_STRIDE + (size_t)d * PLANE + pix;

    #pragma unroll
    for (int r = 0; r < 8; ++r) {
        int c = (r & 3) + 8 * (r >> 2) + 4 * hi;
        float y = acc2[r] + acc3[r] * sigmoidf_fast(acc3[r + 8]);
        obase[(size_t)c * CH_STRIDE] = y;
    }
}

extern "C" void kernel_launch(void* const* d_in, const int* in_sizes, int n_in,
                              void* d_out, int out_size, void* d_ws, size_t ws_size,
                              hipStream_t stream)
{
    const float* inp = (const float*)d_in[0];
    const float* cw  = (const float*)d_in[1];
    const float* w1  = (const float*)d_in[2];
    const float* w2  = (const float*)d_in[3];
    const float* w3  = (const float*)d_in[4];
    const int*   rev = (const int*)d_in[5];

    ushort* wtab  = (ushort*)d_ws;                    // [0, 27648)
    ushort* wtab2 = (ushort*)((char*)d_ws + 27648);   // [27648, 31744)
    char*   xT    = (char*)d_ws + 32768;              // 65,011,712 B

    const size_t xt_bytes = (size_t)4 * BD * 128 * 4096;
    const size_t zf_off   = 32768 + xt_bytes;                   // 65,044,480
    const size_t zf_bytes = (size_t)4 * BD * PLANE * 16 * 4;    // 130,023,424
    const bool fused = (ws_size >= zf_off + zf_bytes);

    __half2* zfp = fused ? (__half2*)((char*)d_ws + zf_off) : (__half2*)d_out;

    wprep_all<<<dim3(62), dim3(256), 0, stream>>>(cw, w1, w2, w3, wtab, wtab2);

    xprep_kernel<<<dim3(7936), dim3(256), 0, stream>>>(inp, xT);

    // 4b * 31d * 64 h-tiles = 7936 blocks (2 rows x 128 w each)
    conv_gates_mfma_fast<<<dim3(7936), dim3(256), 0, stream>>>(
        xT, wtab, zfp);

    if (fused) {
        scanmlp_kernel<<<dim3(512), dim3(256), 0, stream>>>(
            zfp, wtab2, (float*)d_out, rev);
    } else {
        ushort* hbuf = (ushort*)xT;   // reuse xT region after conv
        scan_kernel<<<dim3(4096), dim3(256), 0, stream>>>(
            (const __half2*)d_out, hbuf, rev);
        mlp_mfma_kernel<<<dim3(15872), dim3(256), 0, stream>>>(
            (const char*)hbuf, wtab2, (float*)d_out);
    }
}

// Round 9
// 171.188 us; speedup vs baseline: 1.2714x; 1.2714x over previous
//
#include <hip/hip_runtime.h>
#include <hip/hip_fp16.h>

#define HC 16
#define CIN 16
#define BD 31
#define HH 128
#define WW 128
#define PLANE (HH*WW)           // 16384
#define CH_STRIDE (BD*PLANE)    // 507904

typedef __attribute__((ext_vector_type(8))) short bf16x8;   // 8 bf16 = 4 VGPR
typedef __attribute__((ext_vector_type(16))) float f32x16;  // MFMA 32x32 acc

__device__ __forceinline__ float sigmoidf_fast(float x) {
    return 1.0f / (1.0f + __expf(-x));
}
__device__ __forceinline__ float tanhf_fast(float x) {
    return 2.0f / (1.0f + __expf(-2.0f * x)) - 1.0f;
}
__device__ __forceinline__ ushort f2bf(float f) {   // RNE float->bf16
    unsigned u = __float_as_uint(f);
    u = (u + 0x7fffu + ((u >> 16) & 1u)) >> 16;
    return (ushort)u;
}
// exact-gelu via Abramowitz-Stegun 7.1.26 erf (|eps|<=1.5e-7)
__device__ __forceinline__ float gelu_as(float s) {
    float z  = 0.70710678118f * s;
    float az = fabsf(z);
    float t  = __builtin_amdgcn_rcpf(fmaf(0.3275911f, az, 1.0f));
    float p  = t * (0.254829592f + t * (-0.284496736f + t * (1.421413741f
             + t * (-1.453152027f + t * 1.061405429f))));
    float e  = __expf(-z * z);
    float er = copysignf(1.0f - p * e, z);
    return 0.5f * s * (1.0f + er);
}

// ---------------------------------------------------------------------------
// Merged weight prep.
// idx < 13824: conv wtab[kd][tap][lane][j], co=lane&31, ci=8*(lane>>5)+j.
// next 2048:  MLP wtab2 with k-map k(e,hi) = (e&3)+8*(e>>2)+4*hi for ALL
// tables (B-side now comes straight from the conv C/D fragment, whose
// channel-per-slot map is exactly k(e,hi); shared-k-permutation keeps the
// contraction exact).
//   tbl0: w1^T A-frag (m=j)     tbl3: w3^T A-frag (m = [a|wg] row)
//   tbl1/2: w2 A-frags mf=0/1 (k = k(e,hi)+16*mf on w2's j-axis; m>=16 zero)
// ---------------------------------------------------------------------------
__global__ void wprep_all(const float* __restrict__ cw,
                          const float* __restrict__ w1,
                          const float* __restrict__ w2,
                          const float* __restrict__ w3,
                          ushort* __restrict__ wtab,
                          ushort* __restrict__ wtab2)
{
    int idx = blockIdx.x * 256 + threadIdx.x;
    if (idx < 13824) {
        int j    = idx & 7;
        int lane = (idx >> 3) & 63;
        int t    = (idx >> 9) % 9;
        int kd   = (idx >> 9) / 9;
        int co = lane & 31;
        int ci = 8 * (lane >> 5) + j;
        int kh = t / 3, kw = t % 3;
        wtab[idx] = f2bf(cw[(co * CIN + ci) * 27 + kd * 9 + kh * 3 + kw]);
        return;
    }
    idx -= 13824;
    if (idx >= 2048) return;
    int e    = idx & 7;
    int lane = (idx >> 3) & 63;
    int tbl  = idx >> 9;
    int m  = lane & 31;
    int hi = lane >> 5;
    int k  = (e & 3) + 8 * (e >> 2) + 4 * hi;   // shared k-permutation
    float v = 0.f;
    if (tbl == 0)      v = w1[k * 32 + m];
    else if (tbl == 3) v = w3[k * 32 + m];
    else {
        int mf = tbl - 1;
        if (m < 16) v = w2[(k + 16 * mf) * 16 + m];
    }
    wtab2[idx] = f2bf(v);
}

// ---------------------------------------------------------------------------
// xprep: fp32 [b][ci][d][h][w] -> bf16 rows xT[b][d][h][4096B], ci innermost,
// slab swizzle pre-baked (swizzle-source + linear gload_lds dest, rule #21).
// Swizzle: byte = (wcol*32+cio) ^ ((wcol&0xE)<<3), 512B-group-local, injective.
// ---------------------------------------------------------------------------
__global__ __launch_bounds__(256)
void xprep_kernel(const float* __restrict__ inp, char* __restrict__ xT)
{
    __shared__ float tile[16][256];
    int t  = threadIdx.x;
    int hp = blockIdx.x & 63;
    int g  = blockIdx.x >> 6;
    int d  = g % BD;
    int b  = g / BD;

    size_t src = (size_t)b * CIN * CH_STRIDE + (size_t)d * PLANE + hp * 256;
    #pragma unroll
    for (int c = 0; c < 16; ++c)
        tile[c][t] = inp[src + (size_t)c * CH_STRIDE + t];
    __syncthreads();

    int w  = t & 127;
    int rr = t >> 7;
    char* rowp = xT + (((size_t)(b * BD + d) * 128) + hp * 2 + rr) * 4096;
    #pragma unroll
    for (int q = 0; q < 2; ++q) {
        uint4 pk;
        pk.x = (unsigned)f2bf(tile[q*8+0][t]) | ((unsigned)f2bf(tile[q*8+1][t]) << 16);
        pk.y = (unsigned)f2bf(tile[q*8+2][t]) | ((unsigned)f2bf(tile[q*8+3][t]) << 16);
        pk.z = (unsigned)f2bf(tile[q*8+4][t]) | ((unsigned)f2bf(tile[q*8+5][t]) << 16);
        pk.w = (unsigned)f2bf(tile[q*8+6][t]) | ((unsigned)f2bf(tile[q*8+7][t]) << 16);
        unsigned off = ((unsigned)((w + 1) * 32 + q * 16) ^ (((unsigned)(w + 1) & 0xE) << 3)) - 32;
        *(uint4*)(rowp + off) = pk;
    }
}

// ---------------------------------------------------------------------------
// FUSED conv + scan + MLP. Block = 1 output row x 128 w, one (b,ht), marching
// d in scan order. 4 waves = w-quarters; each wave: M=32co x N=32w implicit
// GEMM (27 MFMA/d) -> gates -> scan state h[8] in regs (conv C/D channel map
// == MLP B-frag k-map, so h never leaves registers) -> 4 MLP MFMAs -> store.
// LDS: 4 rolling plane slots (3 rows x 4224B each); per d stage plane d+2
// into slot (d+2)&3 (overwrites the plane consumed 2 steps ago), ONE
// __syncthreads per d — staging latency hides under the whole compute phase.
// ---------------------------------------------------------------------------
#define SLOT_B (3 * 4224)       // 12672 B per plane slot

__device__ __forceinline__ void gload_lds16(const void* g, void* l) {
    __builtin_amdgcn_global_load_lds(
        (const __attribute__((address_space(1))) unsigned int*)g,
        (__attribute__((address_space(3))) unsigned int*)l, 16, 0, 0);
}

__global__ __launch_bounds__(256, 2)
void qrnn_fused(const char* __restrict__ xT,
                const ushort* __restrict__ wtab,
                const ushort* __restrict__ wtab2,
                float* __restrict__ out,
                const int* __restrict__ rev_p)
{
    __shared__ __align__(16) char slab[4][SLOT_B];

    // grid 512 = 8 XCD x 64: consecutive logical ids share an XCD's L2
    int p = blockIdx.x;
    int logical = (p & 7) * 64 + (p >> 3);
    int b  = logical >> 7;
    int ht = logical & 127;          // one output row per block
    int rev = rev_p[0];

    int lane = threadIdx.x & 63;
    int wid  = threadIdx.x >> 6;     // w-quarter
    int wl   = lane & 31;
    int hi   = lane >> 5;
    int cio  = hi * 16;

    // conv A-frags resident in VGPRs (27 x 16B)
    const bf16x8* wt = (const bf16x8*)wtab;
    bf16x8 af[27];
    #pragma unroll
    for (int t = 0; t < 27; ++t) af[t] = wt[t * 64 + lane];

    const bf16x8* W2 = (const bf16x8*)wtab2;
    bf16x8 af1  = W2[lane];
    bf16x8 af2a = W2[64 + lane];
    bf16x8 af2b = W2[128 + lane];
    bf16x8 af3  = W2[192 + lane];

    // per-lane LDS read offsets within a slot for dwn=0,1,2 (wcol = wid*32+wl+dwn;
    // wid*32 is 0 mod 16 so the XOR bits depend only on wl+dwn)
    unsigned bpo[3];
    #pragma unroll
    for (int dwn = 0; dwn < 3; ++dwn) {
        unsigned wc = (unsigned)(wl + dwn);
        bpo[dwn] = (unsigned)(wid * 1024) + ((wc * 32 + cio) ^ ((wc & 0xE) << 3));
    }

    // zero edge columns of all 4 slots: per row, [0,32) and [4128,4224).
    for (int i = threadIdx.x; i < 4 * 3 * 32; i += 256) {
        int s = i / 96;
        int r = (i / 32) % 3;
        int k = i & 31;
        int off = (k < 8) ? (k * 4) : (4128 + (k - 8) * 4);
        *(int*)(slab[s] + r * 4224 + off) = 0;
    }

    auto zero_slot = [&](int s) {    // interior only (edges already zero)
        for (int i = threadIdx.x; i < 768; i += 256) {
            int r = i >> 8;
            int k = i & 255;
            *(uint4*)(slab[s] + r * 4224 + 32 + k * 16) = uint4{0, 0, 0, 0};
        }
    };

    auto stage = [&](int s, int plane) {
        const char* pl = xT + ((size_t)(b * BD + plane) * 128) * 4096;
        for (int c = wid; c < 12; c += 4) {   // 3 rows x 4 chunks
            int rr = c >> 2, ch = c & 3;
            int h = ht - 1 + rr;
            char* dst = slab[s] + rr * 4224 + 32 + ch * 1024;
            if ((unsigned)h < (unsigned)HH)
                gload_lds16(pl + (size_t)h * 4096 + ch * 1024 + lane * 16, dst);
            else
                *(uint4*)(dst + lane * 16) = uint4{0, 0, 0, 0};
        }
    };

    int d0  = rev ? (BD - 1) : 0;
    int sgn = rev ? -1 : 1;

    // prologue: first two planes in scan order + zero slot for the OOB plane
    stage(d0 & 3, d0);
    stage((d0 + sgn) & 3, d0 + sgn);
    zero_slot((d0 - sgn) & 3);
    __syncthreads();

    f32x16 zacc;
    #pragma unroll
    for (int r = 0; r < 16; ++r) zacc[r] = 0.f;
    float h[8];
    #pragma unroll
    for (int j = 0; j < 8; ++j) h[j] = 0.f;

    float* obase = out + (size_t)b * HC * CH_STRIDE + ht * WW + wid * 32 + wl;

    #pragma unroll 1
    for (int i = 0; i < BD; ++i) {
        int d = d0 + sgn * i;
        int q = d + 2 * sgn;
        if (q >= 0 && q < BD)            stage(q & 3, q);      // block-uniform
        else if (q == (rev ? -1 : BD))   zero_slot(q & 3);

        // conv: 27 MFMAs over planes d-1,d,d+1 (slots (d-1+kd)&3, OOB = zeros)
        f32x16 acc;
        {
            const char* sb = slab[(d - 1) & 3];
            bf16x8 b0 = *(const bf16x8*)(sb + bpo[0]);
            acc = __builtin_amdgcn_mfma_f32_32x32x16_bf16(af[0], b0, zacc, 0, 0, 0);
            #pragma unroll
            for (int t = 1; t < 9; ++t) {
                bf16x8 bfr = *(const bf16x8*)(sb + (t / 3) * 4224 + bpo[t % 3]);
                acc = __builtin_amdgcn_mfma_f32_32x32x16_bf16(af[t], bfr, acc, 0, 0, 0);
            }
        }
        #pragma unroll
        for (int kd = 1; kd < 3; ++kd) {
            const char* sb = slab[(d - 1 + kd) & 3];
            #pragma unroll
            for (int t = 0; t < 9; ++t) {
                bf16x8 bfr = *(const bf16x8*)(sb + (t / 3) * 4224 + bpo[t % 3]);
                acc = __builtin_amdgcn_mfma_f32_32x32x16_bf16(af[kd * 9 + t], bfr, acc, 0, 0, 0);
            }
        }

        // gates + scan update (channel of slot r is k(r,hi) on both sides)
        union { bf16x8 v; unsigned u[4]; } bx;
        #pragma unroll
        for (int r = 0; r < 8; ++r) {
            float z = tanhf_fast(acc[r]);
            float f = sigmoidf_fast(acc[r + 8]);
            h[r] = f * h[r] + (1.f - f) * z;
        }
        #pragma unroll
        for (int qq = 0; qq < 4; ++qq)
            bx.u[qq] = (unsigned)f2bf(h[2 * qq]) | ((unsigned)f2bf(h[2 * qq + 1]) << 16);

        // MLP head
        f32x16 a1 = __builtin_amdgcn_mfma_f32_32x32x16_bf16(af1, bx.v, zacc, 0, 0, 0);
        f32x16 a3 = __builtin_amdgcn_mfma_f32_32x32x16_bf16(af3, bx.v, zacc, 0, 0, 0);

        union { bf16x8 v; unsigned u[4]; } b2a, b2b;
        #pragma unroll
        for (int qq = 0; qq < 4; ++qq) {
            float g0 = gelu_as(a1[2 * qq]);
            float g1 = gelu_as(a1[2 * qq + 1]);
            float g8 = gelu_as(a1[8 + 2 * qq]);
            float g9 = gelu_as(a1[8 + 2 * qq + 1]);
            b2a.u[qq] = (unsigned)f2bf(g0) | ((unsigned)f2bf(g1) << 16);
            b2b.u[qq] = (unsigned)f2bf(g8) | ((unsigned)f2bf(g9) << 16);
        }
        f32x16 a2 = __builtin_amdgcn_mfma_f32_32x32x16_bf16(af2a, b2a.v, zacc, 0, 0, 0);
        a2 = __builtin_amdgcn_mfma_f32_32x32x16_bf16(af2b, b2b.v, a2, 0, 0, 0);

        float* ob = obase + (size_t)d * PLANE;
        #pragma unroll
        for (int r = 0; r < 8; ++r) {
            int c = (r & 3) + 8 * (r >> 2) + 4 * hi;
            ob[(size_t)c * CH_STRIDE] = a2[r] + a3[r] * sigmoidf_fast(a3[r + 8]);
        }

        __syncthreads();   // staged plane landed; safe to rotate slots
    }
}

extern "C" void kernel_launch(void* const* d_in, const int* in_sizes, int n_in,
                              void* d_out, int out_size, void* d_ws, size_t ws_size,
                              hipStream_t stream)
{
    const float* inp = (const float*)d_in[0];
    const float* cw  = (const float*)d_in[1];
    const float* w1  = (const float*)d_in[2];
    const float* w2  = (const float*)d_in[3];
    const float* w3  = (const float*)d_in[4];
    const int*   rev = (const int*)d_in[5];

    ushort* wtab  = (ushort*)d_ws;                    // [0, 27648)
    ushort* wtab2 = (ushort*)((char*)d_ws + 27648);   // [27648, 31744)
    char*   xT    = (char*)d_ws + 32768;              // 65,011,712 B

    wprep_all<<<dim3(62), dim3(256), 0, stream>>>(cw, w1, w2, w3, wtab, wtab2);

    xprep_kernel<<<dim3(7936), dim3(256), 0, stream>>>(inp, xT);

    // 4b x 128ht = 512 blocks (exactly 2 per CU), persistent over all 31 d
    qrnn_fused<<<dim3(512), dim3(256), 0, stream>>>(
        xT, wtab, wtab2, (float*)d_out, rev);
}

// Round 11
// 142.951 us; speedup vs baseline: 1.5225x; 1.1975x over previous
//
#include <hip/hip_runtime.h>
#include <hip/hip_fp16.h>

#define HC 16
#define CIN 16
#define BD 31
#define HH 128
#define WW 128
#define PLANE (HH*WW)           // 16384
#define CH_STRIDE (BD*PLANE)    // 507904

typedef __attribute__((ext_vector_type(8))) short bf16x8;   // 8 bf16 = 4 VGPR
typedef __attribute__((ext_vector_type(16))) float f32x16;  // MFMA 32x32 acc

// fast transcendental forms: v_rcp instead of precise-div (the `/` operator
// emits a ~9-inst div_scale/div_fmas/div_fixup sequence without fast-math).
__device__ __forceinline__ float sigmoid_fast(float x) {
    return __builtin_amdgcn_rcpf(1.0f + __expf(-x));
}
__device__ __forceinline__ float tanh_fast(float x) {
    return fmaf(2.0f, __builtin_amdgcn_rcpf(1.0f + __expf(-2.0f * x)), -1.0f);
}
__device__ __forceinline__ ushort f2bf(float f) {   // RNE float->bf16 (prep paths)
    unsigned u = __float_as_uint(f);
    u = (u + 0x7fffu + ((u >> 16) & 1u)) >> 16;
    return (ushort)u;
}
// packed f32x2 -> bf16x2 via HW cvt_pk (no builtin on gfx950 — inline asm, T12)
__device__ __forceinline__ unsigned pack_bf2(float lo, float hi) {
    unsigned r;
    asm("v_cvt_pk_bf16_f32 %0, %1, %2" : "=v"(r) : "v"(lo), "v"(hi));
    return r;
}
// exact-gelu via Abramowitz-Stegun 7.1.26 erf (|eps|<=1.5e-7)
__device__ __forceinline__ float gelu_as(float s) {
    float z  = 0.70710678118f * s;
    float az = fabsf(z);
    float t  = __builtin_amdgcn_rcpf(fmaf(0.3275911f, az, 1.0f));
    float p  = t * (0.254829592f + t * (-0.284496736f + t * (1.421413741f
             + t * (-1.453152027f + t * 1.061405429f))));
    float e  = __expf(-z * z);
    float er = copysignf(1.0f - p * e, z);
    return 0.5f * s * (1.0f + er);
}

// ---------------------------------------------------------------------------
// Merged weight prep (unchanged from round 9).
// ---------------------------------------------------------------------------
__global__ void wprep_all(const float* __restrict__ cw,
                          const float* __restrict__ w1,
                          const float* __restrict__ w2,
                          const float* __restrict__ w3,
                          ushort* __restrict__ wtab,
                          ushort* __restrict__ wtab2)
{
    int idx = blockIdx.x * 256 + threadIdx.x;
    if (idx < 13824) {
        int j    = idx & 7;
        int lane = (idx >> 3) & 63;
        int t    = (idx >> 9) % 9;
        int kd   = (idx >> 9) / 9;
        int co = lane & 31;
        int ci = 8 * (lane >> 5) + j;
        int kh = t / 3, kw = t % 3;
        wtab[idx] = f2bf(cw[(co * CIN + ci) * 27 + kd * 9 + kh * 3 + kw]);
        return;
    }
    idx -= 13824;
    if (idx >= 2048) return;
    int e    = idx & 7;
    int lane = (idx >> 3) & 63;
    int tbl  = idx >> 9;
    int m  = lane & 31;
    int hi = lane >> 5;
    int k  = (e & 3) + 8 * (e >> 2) + 4 * hi;   // shared k-permutation
    float v = 0.f;
    if (tbl == 0)      v = w1[k * 32 + m];
    else if (tbl == 3) v = w3[k * 32 + m];
    else {
        int mf = tbl - 1;
        if (m < 16) v = w2[(k + 16 * mf) * 16 + m];
    }
    wtab2[idx] = f2bf(v);
}

// ---------------------------------------------------------------------------
// xprep (unchanged): fp32 -> bf16 rows xT[b][d][h][4096B], swizzle pre-baked.
// ---------------------------------------------------------------------------
__global__ __launch_bounds__(256)
void xprep_kernel(const float* __restrict__ inp, char* __restrict__ xT)
{
    __shared__ float tile[16][256];
    int t  = threadIdx.x;
    int hp = blockIdx.x & 63;
    int g  = blockIdx.x >> 6;
    int d  = g % BD;
    int b  = g / BD;

    size_t src = (size_t)b * CIN * CH_STRIDE + (size_t)d * PLANE + hp * 256;
    #pragma unroll
    for (int c = 0; c < 16; ++c)
        tile[c][t] = inp[src + (size_t)c * CH_STRIDE + t];
    __syncthreads();

    int w  = t & 127;
    int rr = t >> 7;
    char* rowp = xT + (((size_t)(b * BD + d) * 128) + hp * 2 + rr) * 4096;
    #pragma unroll
    for (int q = 0; q < 2; ++q) {
        uint4 pk;
        pk.x = (unsigned)f2bf(tile[q*8+0][t]) | ((unsigned)f2bf(tile[q*8+1][t]) << 16);
        pk.y = (unsigned)f2bf(tile[q*8+2][t]) | ((unsigned)f2bf(tile[q*8+3][t]) << 16);
        pk.z = (unsigned)f2bf(tile[q*8+4][t]) | ((unsigned)f2bf(tile[q*8+5][t]) << 16);
        pk.w = (unsigned)f2bf(tile[q*8+6][t]) | ((unsigned)f2bf(tile[q*8+7][t]) << 16);
        unsigned off = ((unsigned)((w + 1) * 32 + q * 16) ^ (((unsigned)(w + 1) & 0xE) << 3)) - 32;
        *(uint4*)(rowp + off) = pk;
    }
}

// ---------------------------------------------------------------------------
// FUSED conv+scan+MLP, SOFTWARE-PIPELINED (T15): per iteration, conv(d)'s 27
// MFMAs are issued alongside tail(d-1)'s VALU work (gates/scan/MLP/gelu) —
// independent chains, so the scheduler fills MFMA latency with VALU and
// vice versa. One barrier per d. 4 rolling plane slots as in round 9.
// ---------------------------------------------------------------------------
#define SLOT_B (3 * 4224)       // 12672 B per plane slot

__device__ __forceinline__ void gload_lds16(const void* g, void* l) {
    __builtin_amdgcn_global_load_lds(
        (const __attribute__((address_space(1))) unsigned int*)g,
        (__attribute__((address_space(3))) unsigned int*)l, 16, 0, 0);
}

__global__ __launch_bounds__(256, 2)
void qrnn_fused(const char* __restrict__ xT,
                const ushort* __restrict__ wtab,
                const ushort* __restrict__ wtab2,
                float* __restrict__ out,
                const int* __restrict__ rev_p)
{
    __shared__ __align__(16) char slab[4][SLOT_B];

    // grid 512 = 8 XCD x 64: consecutive logical ids share an XCD's L2
    int p = blockIdx.x;
    int logical = (p & 7) * 64 + (p >> 3);
    int b  = logical >> 7;
    int ht = logical & 127;          // one output row per block
    int rev = rev_p[0];

    int lane = threadIdx.x & 63;
    int wid  = threadIdx.x >> 6;     // w-quarter
    int wl   = lane & 31;
    int hi   = lane >> 5;
    int cio  = hi * 16;

    // conv A-frags resident (27 x 16B)
    const bf16x8* wt = (const bf16x8*)wtab;
    bf16x8 af[27];
    #pragma unroll
    for (int t = 0; t < 27; ++t) af[t] = wt[t * 64 + lane];

    const bf16x8* W2 = (const bf16x8*)wtab2;
    bf16x8 af1  = W2[lane];
    bf16x8 af2a = W2[64 + lane];
    bf16x8 af2b = W2[128 + lane];
    bf16x8 af3  = W2[192 + lane];

    // per-lane LDS read offsets within a slot for dwn=0,1,2
    unsigned bpo[3];
    #pragma unroll
    for (int dwn = 0; dwn < 3; ++dwn) {
        unsigned wc = (unsigned)(wl + dwn);
        bpo[dwn] = (unsigned)(wid * 1024) + ((wc * 32 + cio) ^ ((wc & 0xE) << 3));
    }

    // zero edge columns of all 4 slots
    for (int i = threadIdx.x; i < 4 * 3 * 32; i += 256) {
        int s = i / 96;
        int r = (i / 32) % 3;
        int k = i & 31;
        int off = (k < 8) ? (k * 4) : (4128 + (k - 8) * 4);
        *(int*)(slab[s] + r * 4224 + off) = 0;
    }

    auto zero_slot = [&](int s) {    // interior only (edges already zero)
        for (int i = threadIdx.x; i < 768; i += 256) {
            int r = i >> 8;
            int k = i & 255;
            *(uint4*)(slab[s] + r * 4224 + 32 + k * 16) = uint4{0, 0, 0, 0};
        }
    };

    auto stage = [&](int s, int plane) {
        const char* pl = xT + ((size_t)(b * BD + plane) * 128) * 4096;
        for (int c = wid; c < 12; c += 4) {   // 3 rows x 4 chunks
            int rr = c >> 2, ch = c & 3;
            int h = ht - 1 + rr;
            char* dst = slab[s] + rr * 4224 + 32 + ch * 1024;
            if ((unsigned)h < (unsigned)HH)
                gload_lds16(pl + (size_t)h * 4096 + ch * 1024 + lane * 16, dst);
            else
                *(uint4*)(dst + lane * 16) = uint4{0, 0, 0, 0};
        }
    };

    f32x16 zacc;
    #pragma unroll
    for (int r = 0; r < 16; ++r) zacc[r] = 0.f;

    auto convd = [&](int d) -> f32x16 {
        f32x16 A = zacc;
        #pragma unroll
        for (int kd = 0; kd < 3; ++kd) {
            const char* sb = slab[(d - 1 + kd) & 3];   // OOB slots hold zeros
            #pragma unroll
            for (int t = 0; t < 9; ++t) {
                bf16x8 bfr = *(const bf16x8*)(sb + (t / 3) * 4224 + bpo[t % 3]);
                A = __builtin_amdgcn_mfma_f32_32x32x16_bf16(af[kd * 9 + t], bfr, A, 0, 0, 0);
            }
        }
        return A;
    };

    float h[8];
    #pragma unroll
    for (int j = 0; j < 8; ++j) h[j] = 0.f;

    float* obase = out + (size_t)b * HC * CH_STRIDE + ht * WW + wid * 32 + wl;

    // tail: gates -> scan -> MLP -> store for plane d, given conv acc A.
    auto tail = [&](const f32x16& A, int d) {
        union { bf16x8 v; unsigned u[4]; } bx;
        #pragma unroll
        for (int r = 0; r < 8; ++r) {
            float z = tanh_fast(A[r]);
            float f = sigmoid_fast(A[r + 8]);
            h[r] = z + f * (h[r] - z);          // f*h + (1-f)*z
        }
        #pragma unroll
        for (int q = 0; q < 4; ++q)
            bx.u[q] = pack_bf2(h[2 * q], h[2 * q + 1]);

        f32x16 a1 = __builtin_amdgcn_mfma_f32_32x32x16_bf16(af1, bx.v, zacc, 0, 0, 0);
        f32x16 a3 = __builtin_amdgcn_mfma_f32_32x32x16_bf16(af3, bx.v, zacc, 0, 0, 0);

        union { bf16x8 v; unsigned u[4]; } b2a, b2b;
        #pragma unroll
        for (int q = 0; q < 4; ++q) {
            b2a.u[q] = pack_bf2(gelu_as(a1[2 * q]),     gelu_as(a1[2 * q + 1]));
            b2b.u[q] = pack_bf2(gelu_as(a1[8 + 2 * q]), gelu_as(a1[8 + 2 * q + 1]));
        }
        f32x16 a2 = __builtin_amdgcn_mfma_f32_32x32x16_bf16(af2a, b2a.v, zacc, 0, 0, 0);
        a2 = __builtin_amdgcn_mfma_f32_32x32x16_bf16(af2b, b2b.v, a2, 0, 0, 0);

        float* ob = obase + (size_t)d * PLANE;
        #pragma unroll
        for (int r = 0; r < 8; ++r) {
            int c = (r & 3) + 8 * (r >> 2) + 4 * hi;
            ob[(size_t)c * CH_STRIDE] = a2[r] + a3[r] * sigmoid_fast(a3[r + 8]);
        }
    };

    int d0  = rev ? (BD - 1) : 0;
    int sgn = rev ? -1 : 1;
    int oobq = rev ? -1 : BD;       // first OOB plane index past the end

    // prologue: planes d0, d0+sgn in flight; OOB slot zeroed
    stage(d0 & 3, d0);
    stage((d0 + sgn) & 3, d0 + sgn);
    zero_slot((d0 - sgn) & 3);
    __syncthreads();

    // peeled first iteration (no tail yet)
    f32x16 accP;
    {
        int q = d0 + 2 * sgn;
        if (q >= 0 && q < BD) stage(q & 3, q);
        accP = convd(d0);
        __syncthreads();
    }

    #pragma unroll 1
    for (int i = 1; i < BD; ++i) {
        int d = d0 + sgn * i;
        int q = d + 2 * sgn;
        if (q >= 0 && q < BD) stage(q & 3, q);      // block-uniform branches
        else if (q == oobq)   zero_slot(q & 3);

        f32x16 acc = convd(d);      // 27 MFMAs — independent of tail below
        tail(accP, d - sgn);        // VALU chain for previous d: interleaves
        accP = acc;

        __syncthreads();            // staged plane landed; slots rotate
    }
    tail(accP, d0 + sgn * (BD - 1));
}

extern "C" void kernel_launch(void* const* d_in, const int* in_sizes, int n_in,
                              void* d_out, int out_size, void* d_ws, size_t ws_size,
                              hipStream_t stream)
{
    const float* inp = (const float*)d_in[0];
    const float* cw  = (const float*)d_in[1];
    const float* w1  = (const float*)d_in[2];
    const float* w2  = (const float*)d_in[3];
    const float* w3  = (const float*)d_in[4];
    const int*   rev = (const int*)d_in[5];

    ushort* wtab  = (ushort*)d_ws;                    // [0, 27648)
    ushort* wtab2 = (ushort*)((char*)d_ws + 27648);   // [27648, 31744)
    char*   xT    = (char*)d_ws + 32768;              // 65,011,712 B

    wprep_all<<<dim3(62), dim3(256), 0, stream>>>(cw, w1, w2, w3, wtab, wtab2);

    xprep_kernel<<<dim3(7936), dim3(256), 0, stream>>>(inp, xT);

    // 4b x 128ht = 512 blocks (2 per CU), persistent over all 31 d
    qrnn_fused<<<dim3(512), dim3(256), 0, stream>>>(
        xT, wtab, wtab2, (float*)d_out, rev);
}